// Round 1
// baseline (849.052 us; speedup 1.0000x reference)
//
#include <hip/hip_runtime.h>
#include <cstdint>

#define EPS 1e-5f
constexpr int B = 4, C = 512, HW = 16384, K = 32;

// workspace layout in floats
constexpr size_t Z_OFF      = 0;                              // [B][HW][C]
constexpr size_t ASSIGN_OFF = (size_t)B * HW * C;             // [B][HW][K]
constexpr size_t AGG_OFF    = ASSIGN_OFF + (size_t)B * HW * K; // [B][K][C]
constexpr size_t ASUM_OFF   = AGG_OFF + (size_t)B * K * C;     // [B][K]
constexpr size_t C2_OFF     = ASUM_OFF + (size_t)B * K;        // [K]
constexpr size_t GAMMA_OFF  = C2_OFF + (size_t)K;              // [B][C]

// ---------------------------------------------------------------------------
// prep: zero agg+asum, compute c2[k] = sum_c cw[k,c]^2
__global__ __launch_bounds__(256) void prep_kernel(const float* __restrict__ cw,
                                                   float* __restrict__ ws) {
    int idx = blockIdx.x * 256 + threadIdx.x;
    int nz = B * K * C + B * K;  // agg + asum contiguous
    if (idx < nz) ws[AGG_OFF + idx] = 0.f;
    if (blockIdx.x == 0 && threadIdx.x < K) {
        float s = 0.f;
        for (int c = 0; c < C; c++) {
            float v = cw[threadIdx.x * C + c];
            s += v * v;
        }
        ws[C2_OFF + threadIdx.x] = s;
    }
}

// ---------------------------------------------------------------------------
// conv 1x1 + BN2 + ReLU: z[b][n][o] = relu(bn(sum_c W[o,c]*x[b,c,n]))
// 128x128 tile, BK=32, 256 threads, 8x8 micro-tile per thread.
__global__ __launch_bounds__(256) void conv_bn_relu_kernel(
    const float* __restrict__ x, const float* __restrict__ w,
    const float* __restrict__ g2, const float* __restrict__ b2,
    const float* __restrict__ m2, const float* __restrict__ v2,
    float* __restrict__ z) {
    __shared__ float Xs[32][128];  // [c][n]
    __shared__ float Wt[32][128];  // [c][o]
    const int tid = threadIdx.x;
    const int n0 = blockIdx.x * 128;
    const int o0 = blockIdx.y * 128;
    const int b  = blockIdx.z;
    const int tx = tid & 15, ty = tid >> 4;  // tx->o, ty->n
    float acc[8][8] = {};

    for (int c0 = 0; c0 < C; c0 += 32) {
        #pragma unroll
        for (int p = 0; p < 4; p++) {
            int lin = tid + p * 256;                 // 0..1023
            int row = lin >> 5, col = (lin & 31) << 2;
            float4 xv = *(const float4*)&x[((size_t)(b * C + c0 + row)) * HW + n0 + col];
            *(float4*)&Xs[row][col] = xv;
            int o = lin >> 3, cc4 = (lin & 7) << 2;
            float4 wv = *(const float4*)&w[(size_t)(o0 + o) * C + c0 + cc4];
            Wt[cc4 + 0][o] = wv.x; Wt[cc4 + 1][o] = wv.y;
            Wt[cc4 + 2][o] = wv.z; Wt[cc4 + 3][o] = wv.w;
        }
        __syncthreads();
        #pragma unroll 8
        for (int kk = 0; kk < 32; kk++) {
            float a[8], bb[8];
            *(float4*)&a[0]  = *(const float4*)&Xs[kk][ty * 8];
            *(float4*)&a[4]  = *(const float4*)&Xs[kk][ty * 8 + 4];
            *(float4*)&bb[0] = *(const float4*)&Wt[kk][tx * 8];
            *(float4*)&bb[4] = *(const float4*)&Wt[kk][tx * 8 + 4];
            #pragma unroll
            for (int i = 0; i < 8; i++)
                #pragma unroll
                for (int j = 0; j < 8; j++)
                    acc[i][j] += a[i] * bb[j];
        }
        __syncthreads();
    }
    float sc[8], bi[8];
    #pragma unroll
    for (int j = 0; j < 8; j++) {
        int o = o0 + tx * 8 + j;
        float s = g2[o] * rsqrtf(v2[o] + EPS);
        sc[j] = s; bi[j] = b2[o] - m2[o] * s;
    }
    #pragma unroll
    for (int i = 0; i < 8; i++) {
        int n = n0 + ty * 8 + i;
        float r[8];
        #pragma unroll
        for (int j = 0; j < 8; j++) r[j] = fmaxf(acc[i][j] * sc[j] + bi[j], 0.f);
        float* zp = &z[((size_t)b * HW + n) * C + o0 + tx * 8];
        *(float4*)zp       = make_float4(r[0], r[1], r[2], r[3]);
        *(float4*)(zp + 4) = make_float4(r[4], r[5], r[6], r[7]);
    }
}

// ---------------------------------------------------------------------------
// assign: xc = z . cw^T, scaled_l2, softmax over K, write assign, accumulate asum
// block: 128 n's x all 32 k. thread: k = tid&31, 16 n's.
__global__ __launch_bounds__(256) void assign_kernel(
    const float* __restrict__ cw, const float* __restrict__ scale,
    float* __restrict__ ws) {
    const float* z = ws + Z_OFF;
    float* assign  = ws + ASSIGN_OFF;
    const float* c2 = ws + C2_OFF;
    float* asum    = ws + ASUM_OFF;
    __shared__ float zs[128][36];
    __shared__ float cws[32][36];
    __shared__ float x2s[128];
    __shared__ float asum_sh[32][9];
    const int tid = threadIdx.x;
    const int n0 = blockIdx.x * 128;
    const int b  = blockIdx.y;
    const int k = tid & 31, g = tid >> 5;  // g in 0..7
    float acc[16] = {};
    float x2r = 0.f;

    for (int c0 = 0; c0 < C; c0 += 32) {
        #pragma unroll
        for (int p = 0; p < 4; p++) {
            int lin = tid + p * 256;
            int row = lin >> 3, col = (lin & 7) << 2;
            float4 v = *(const float4*)&z[((size_t)b * HW + n0 + row) * C + c0 + col];
            *(float4*)&zs[row][col] = v;
        }
        {
            int row = tid >> 3, col = (tid & 7) << 2;
            float4 v = *(const float4*)&cw[(size_t)row * C + c0 + col];
            *(float4*)&cws[row][col] = v;
        }
        __syncthreads();
        if (tid < 128) {
            #pragma unroll
            for (int cc4 = 0; cc4 < 8; cc4++) {
                float4 v = *(const float4*)&zs[tid][cc4 * 4];
                x2r += v.x * v.x + v.y * v.y + v.z * v.z + v.w * v.w;
            }
        }
        float4 cwr[8];
        #pragma unroll
        for (int cc4 = 0; cc4 < 8; cc4++) cwr[cc4] = *(const float4*)&cws[k][cc4 * 4];
        #pragma unroll
        for (int i = 0; i < 16; i++) {
            int n = g * 16 + i;
            float s = 0.f;
            #pragma unroll
            for (int cc4 = 0; cc4 < 8; cc4++) {
                float4 zv = *(const float4*)&zs[n][cc4 * 4];
                s += zv.x * cwr[cc4].x + zv.y * cwr[cc4].y
                   + zv.z * cwr[cc4].z + zv.w * cwr[cc4].w;
            }
            acc[i] += s;
        }
        __syncthreads();
    }
    if (tid < 128) x2s[tid] = x2r;
    __syncthreads();

    const float scl = scale[k], c2k = c2[k];
    float lsum = 0.f;
    for (int i = 0; i < 16; i++) {
        int n = g * 16 + i;
        float sl = scl * (x2s[n] - 2.f * acc[i] + c2k);
        float m = sl;
        #pragma unroll
        for (int d = 16; d >= 1; d >>= 1) m = fmaxf(m, __shfl_xor(m, d));
        float e = __expf(sl - m);
        float ssum = e;
        #pragma unroll
        for (int d = 16; d >= 1; d >>= 1) ssum += __shfl_xor(ssum, d);
        float a = e / ssum;
        assign[((size_t)b * HW + n0 + n) * K + k] = a;
        lsum += a;
    }
    asum_sh[k][g] = lsum;
    __syncthreads();
    if (tid < 32) {
        float s = 0.f;
        #pragma unroll
        for (int gg = 0; gg < 8; gg++) s += asum_sh[tid][gg];
        atomicAdd(&asum[b * K + tid], s);
    }
}

// ---------------------------------------------------------------------------
// agg[b][k][c] += sum_n assign[b,n,k] * z[b,n,c]  (256-n chunks, atomics)
__global__ __launch_bounds__(512) void agg_kernel(float* __restrict__ ws) {
    const float* z      = ws + Z_OFF;
    const float* assign = ws + ASSIGN_OFF;
    float* agg          = ws + AGG_OFF;
    const int tid = threadIdx.x;          // c
    const int n0 = blockIdx.x * 256;
    const int b  = blockIdx.y;
    float acc[K] = {};
    for (int jb = 0; jb < 256; jb += 8) {
        float zv[8];
        #pragma unroll
        for (int j = 0; j < 8; j++)
            zv[j] = z[((size_t)b * HW + n0 + jb + j) * C + tid];
        #pragma unroll
        for (int j = 0; j < 8; j++) {
            const float* ar = &assign[((size_t)b * HW + n0 + jb + j) * K];  // uniform -> s_load
            #pragma unroll
            for (int kk = 0; kk < K; kk++) acc[kk] += ar[kk] * zv[j];
        }
    }
    #pragma unroll
    for (int kk = 0; kk < K; kk++)
        atomicAdd(&agg[((size_t)b * K + kk) * C + tid], acc[kk]);
}

// ---------------------------------------------------------------------------
// feat = mean_k relu(bn1(agg - asum*cw)); gamma = sigmoid(fc_w @ feat + fc_b)
__global__ __launch_bounds__(512) void feat_kernel(
    const float* __restrict__ cw,
    const float* __restrict__ g1, const float* __restrict__ b1,
    const float* __restrict__ m1, const float* __restrict__ v1,
    const float* __restrict__ fcw, const float* __restrict__ fcb,
    float* __restrict__ ws, float* __restrict__ out_feat) {
    const float* agg  = ws + AGG_OFF;
    const float* asum = ws + ASUM_OFF;
    float* gamma      = ws + GAMMA_OFF;
    __shared__ float featL[C];
    const int tid = threadIdx.x;  // c
    const int b = blockIdx.x;
    float f = 0.f;
    for (int kk = 0; kk < K; kk++) {
        float s = g1[kk] * rsqrtf(v1[kk] + EPS);
        float bias = b1[kk] - m1[kk] * s;
        float e = agg[((size_t)b * K + kk) * C + tid] - asum[b * K + kk] * cw[kk * C + tid];
        f += fmaxf(e * s + bias, 0.f);
    }
    f *= (1.f / 32.f);
    out_feat[b * C + tid] = f;
    featL[tid] = f;
    __syncthreads();
    const int w = tid >> 6, l = tid & 63;
    for (int cc = w * 64; cc < w * 64 + 64; cc++) {
        const float* row = &fcw[(size_t)cc * C + l * 8];
        float4 fa = *(const float4*)&featL[l * 8];
        float4 fb = *(const float4*)&featL[l * 8 + 4];
        float4 wa = *(const float4*)row;
        float4 wb = *(const float4*)(row + 4);
        float s = fa.x * wa.x + fa.y * wa.y + fa.z * wa.z + fa.w * wa.w
                + fb.x * wb.x + fb.y * wb.y + fb.z * wb.z + fb.w * wb.w;
        #pragma unroll
        for (int d = 32; d >= 1; d >>= 1) s += __shfl_xor(s, d);
        if (l == 0) gamma[b * C + cc] = 1.f / (1.f + __expf(-(s + fcb[cc])));
    }
}

// ---------------------------------------------------------------------------
// out = relu(x * (1 + gamma[b,c]))
__global__ __launch_bounds__(256) void gate_kernel(const float* __restrict__ x,
                                                   const float* __restrict__ gamma,
                                                   float* __restrict__ out) {
    size_t idx = (size_t)blockIdx.x * 256 + threadIdx.x;  // float4 index
    int bc = (int)(idx >> 12);                            // / (HW/4)
    float gm = 1.f + gamma[bc];
    float4 xv = ((const float4*)x)[idx];
    float4 r;
    r.x = fmaxf(xv.x * gm, 0.f);
    r.y = fmaxf(xv.y * gm, 0.f);
    r.z = fmaxf(xv.z * gm, 0.f);
    r.w = fmaxf(xv.w * gm, 0.f);
    ((float4*)out)[idx] = r;
}

// ---------------------------------------------------------------------------
extern "C" void kernel_launch(void* const* d_in, const int* in_sizes, int n_in,
                              void* d_out, int out_size, void* d_ws, size_t ws_size,
                              hipStream_t stream) {
    const float* x      = (const float*)d_in[0];
    const float* conv_w = (const float*)d_in[1];
    const float* bn2_g  = (const float*)d_in[2];
    const float* bn2_b  = (const float*)d_in[3];
    const float* bn2_m  = (const float*)d_in[4];
    const float* bn2_v  = (const float*)d_in[5];
    const float* cw     = (const float*)d_in[6];
    const float* scale  = (const float*)d_in[7];
    const float* bn1_g  = (const float*)d_in[8];
    const float* bn1_b  = (const float*)d_in[9];
    const float* bn1_m  = (const float*)d_in[10];
    const float* bn1_v  = (const float*)d_in[11];
    const float* fcw    = (const float*)d_in[12];
    const float* fcb    = (const float*)d_in[13];
    float* ws  = (float*)d_ws;
    float* out = (float*)d_out;

    prep_kernel<<<257, 256, 0, stream>>>(cw, ws);
    conv_bn_relu_kernel<<<dim3(128, 4, 4), 256, 0, stream>>>(
        x, conv_w, bn2_g, bn2_b, bn2_m, bn2_v, ws + Z_OFF);
    assign_kernel<<<dim3(128, 4), 256, 0, stream>>>(cw, scale, ws);
    agg_kernel<<<dim3(64, 4), 512, 0, stream>>>(ws);
    feat_kernel<<<4, 512, 0, stream>>>(cw, bn1_g, bn1_b, bn1_m, bn1_v,
                                       fcw, fcb, ws, out);
    gate_kernel<<<32768, 256, 0, stream>>>(x, ws + GAMMA_OFF, out + B * C);
}

// Round 2
// 517.064 us; speedup vs baseline: 1.6421x; 1.6421x over previous
//
#include <hip/hip_runtime.h>
#include <cstdint>

#define EPS 1e-5f
constexpr int B = 4, C = 512, HW = 16384, K = 32;

typedef __bf16 bf16x8 __attribute__((ext_vector_type(8)));
typedef float  floatx4 __attribute__((ext_vector_type(4)));
typedef unsigned int u32;

__device__ __forceinline__ void load_lds16(const void* g, void* l) {
    __builtin_amdgcn_global_load_lds((const __attribute__((address_space(1))) u32*)g,
                                     (__attribute__((address_space(3))) u32*)l,
                                     16, 0, 0);
}

// ---------------------------------------------------------------------------
// workspace byte offsets
// XB [b][n][c] bf16 (dead after conv; PART/AGG/GAMMA overlay it afterwards)
constexpr size_t XB_OFF    = 0;            // 67,108,864
constexpr size_t PART_OFF  = 0;            // 16,777,216 (fp32, post-conv overlay)
constexpr size_t AGG_OFF   = 16777216;     // 262,144
constexpr size_t GAMMA_OFF = 17039360;     // 8,192
constexpr size_t ZB_OFF    = 67108864;     // 67,108,864 bf16 [b][n][c]
constexpr size_t WBB_OFF   = 134217728;    // 524,288 bf16 [o][c]
constexpr size_t CWB_OFF   = 134742016;    // 32,768 bf16 [k][c]
constexpr size_t AT_OFF    = 134774784;    // 4,194,304 bf16 [b][k][n]
constexpr size_t X2_OFF    = 138969088;    // 262,144 fp32 [b*HW]
constexpr size_t C2_OFF    = 139231232;    // 128
constexpr size_t ASUM_OFF  = 139231360;    // 512

// ---------------------------------------------------------------------------
// prep: convert conv_w and codewords to bf16; c2[k]; zero asum
__global__ __launch_bounds__(256) void prep_kernel(
    const float* __restrict__ conv_w, const float* __restrict__ cw,
    __bf16* __restrict__ wbb, __bf16* __restrict__ cwb,
    float* __restrict__ c2, float* __restrict__ asum) {
    const int tid = threadIdx.x;
    if (blockIdx.x < 68) {
        int idx = (blockIdx.x * 256 + tid) * 16;
        const float* s;
        __bf16* d;
        if (idx < 262144) { s = conv_w + idx; d = wbb + idx; }
        else              { s = cw + (idx - 262144); d = cwb + (idx - 262144); }
        bf16x8 o0, o1;
        #pragma unroll
        for (int j = 0; j < 8; j++) o0[j] = (__bf16)s[j];
        #pragma unroll
        for (int j = 0; j < 8; j++) o1[j] = (__bf16)s[8 + j];
        *(bf16x8*)&d[0] = o0;
        *(bf16x8*)&d[8] = o1;
    } else {
        if (tid < 32) {
            const float* r = cw + tid * 512;
            float s = 0.f;
            for (int c = 0; c < 512; c++) s += r[c] * r[c];
            c2[tid] = s;
        }
        if (tid < 128) asum[tid] = 0.f;
    }
}

// ---------------------------------------------------------------------------
// transpose + convert: x [b][c][n] fp32 -> xb [b][n][c] bf16
__global__ __launch_bounds__(256) void transpose_cvt_kernel(
    const float* __restrict__ x, __bf16* __restrict__ xb) {
    __shared__ float T[64][65];
    const int tid = threadIdx.x;
    const int n0 = blockIdx.x * 64;
    const int c0 = blockIdx.y * 64;
    const int b  = blockIdx.z;
    #pragma unroll
    for (int p = 0; p < 4; p++) {
        int r = (tid >> 4) + p * 16;
        int col = (tid & 15) * 4;
        float4 v = *(const float4*)&x[((size_t)(b * C + c0 + r)) * HW + n0 + col];
        T[r][col] = v.x; T[r][col + 1] = v.y; T[r][col + 2] = v.z; T[r][col + 3] = v.w;
    }
    __syncthreads();
    #pragma unroll
    for (int p = 0; p < 2; p++) {
        int lin = p * 256 + tid;
        int nr = lin >> 3;
        int c8 = (lin & 7) * 8;
        bf16x8 ov;
        #pragma unroll
        for (int j = 0; j < 8; j++) ov[j] = (__bf16)T[c8 + j][nr];
        *(bf16x8*)&xb[((size_t)(b * HW + n0 + nr)) * C + c0 + c8] = ov;
    }
}

// ---------------------------------------------------------------------------
// conv 1x1 as bf16 MFMA GEMM + BN2 + ReLU -> z bf16 [b][n][c]
// 128x128 tile, BK=32, 256 threads (4 waves, 2x2 of 64x64 wave tiles)
__global__ __launch_bounds__(256) void conv_gemm_kernel(
    const __bf16* __restrict__ xb, const __bf16* __restrict__ wbb,
    const float* __restrict__ g2, const float* __restrict__ b2,
    const float* __restrict__ m2, const float* __restrict__ v2,
    __bf16* __restrict__ z) {
    __shared__ __bf16 As[128 * 32];
    __shared__ __bf16 Bs[128 * 32];
    const int tid = threadIdx.x, lane = tid & 63, w = tid >> 6;
    const int wm = w >> 1, wn = w & 1;
    const int l15 = lane & 15, q = lane >> 4;
    const int n0 = blockIdx.x * 128, o0 = blockIdx.y * 128, b = blockIdx.z;

    const __bf16* agp[2]; const __bf16* bgp[2];
    __bf16 *alp[2], *blp[2];
    #pragma unroll
    for (int p = 0; p < 2; p++) {
        int lin = p * 256 + tid, r = lin >> 2, cc = (lin & 3) * 8;
        agp[p] = xb + ((size_t)(b * HW + n0 + r)) * C + cc;
        alp[p] = As + lin * 8;
        bgp[p] = wbb + ((size_t)(o0 + r)) * C + cc;
        blp[p] = Bs + lin * 8;
    }
    floatx4 acc[4][4];
    const floatx4 z4 = {0.f, 0.f, 0.f, 0.f};
    #pragma unroll
    for (int mt = 0; mt < 4; mt++)
        #pragma unroll
        for (int nt = 0; nt < 4; nt++) acc[mt][nt] = z4;

    for (int c0 = 0; c0 < C; c0 += 32) {
        #pragma unroll
        for (int p = 0; p < 2; p++) {
            load_lds16(agp[p] + c0, alp[p]);
            load_lds16(bgp[p] + c0, blp[p]);
        }
        __syncthreads();
        bf16x8 af[4], bfv[4];
        #pragma unroll
        for (int t = 0; t < 4; t++) {
            af[t]  = *(const bf16x8*)&As[(wm * 64 + t * 16 + l15) * 32 + q * 8];
            bfv[t] = *(const bf16x8*)&Bs[(wn * 64 + t * 16 + l15) * 32 + q * 8];
        }
        #pragma unroll
        for (int mt = 0; mt < 4; mt++)
            #pragma unroll
            for (int nt = 0; nt < 4; nt++)
                acc[mt][nt] = __builtin_amdgcn_mfma_f32_16x16x32_bf16(
                    af[mt], bfv[nt], acc[mt][nt], 0, 0, 0);
        __syncthreads();
    }
    #pragma unroll
    for (int nt = 0; nt < 4; nt++) {
        int o = o0 + wn * 64 + nt * 16 + l15;
        float s = g2[o] * rsqrtf(v2[o] + EPS);
        float bi = b2[o] - m2[o] * s;
        #pragma unroll
        for (int mt = 0; mt < 4; mt++) {
            int rbase = n0 + wm * 64 + mt * 16 + q * 4;
            #pragma unroll
            for (int reg = 0; reg < 4; reg++) {
                float v = fmaxf(acc[mt][nt][reg] * s + bi, 0.f);
                z[((size_t)(b * HW + rbase + reg)) * C + o] = (__bf16)v;
            }
        }
    }
}

// ---------------------------------------------------------------------------
// x2[row] = sum_c z[row][c]^2   (row = b*HW + n)
__global__ __launch_bounds__(256) void x2_kernel(const __bf16* __restrict__ z,
                                                 float* __restrict__ x2) {
    const int w = threadIdx.x >> 6, lane = threadIdx.x & 63;
    const int row = blockIdx.x * 4 + w;
    bf16x8 v = *(const bf16x8*)&z[(size_t)row * C + lane * 8];
    float s = 0.f;
    #pragma unroll
    for (int j = 0; j < 8; j++) { float f = (float)v[j]; s += f * f; }
    #pragma unroll
    for (int d = 32; d >= 1; d >>= 1) s += __shfl_xor(s, d);
    if (lane == 0) x2[row] = s;
}

// ---------------------------------------------------------------------------
// assign via MFMA: xc = cw . z^T, softmax over k, write at[b][k][n] bf16 + asum
// block: 256 n (4 waves x 64 n). A = cwb (LDS), B = z tiles (global_load_lds).
__global__ __launch_bounds__(256) void assign_mfma_kernel(
    const __bf16* __restrict__ zb, const __bf16* __restrict__ cwb,
    const float* __restrict__ scale, const float* __restrict__ c2,
    const float* __restrict__ x2, __bf16* __restrict__ at,
    float* __restrict__ asum) {
    __shared__ __bf16 cws[32 * 520];   // padded rows (520 shorts) for bank spread
    __shared__ __bf16 Zs[256 * 32];    // [n][c] 16 KB
    __shared__ float asum_l[32];
    const int tid = threadIdx.x, lane = tid & 63, w = tid >> 6;
    const int l15 = lane & 15, q = lane >> 4;
    const int b = blockIdx.y;
    const int nb = blockIdx.x * 256;

    #pragma unroll
    for (int p = 0; p < 8; p++) {
        int lin = p * 256 + tid;
        int k = lin >> 6, cc8 = (lin & 63) * 8;
        *(bf16x8*)&cws[k * 520 + cc8] = *(const bf16x8*)&cwb[lin * 8];
    }
    if (tid < 32) asum_l[tid] = 0.f;
    __syncthreads();

    const __bf16* zbase = zb + (size_t)(b * HW + nb) * C;
    floatx4 acc[2][4];
    const floatx4 z4 = {0.f, 0.f, 0.f, 0.f};
    #pragma unroll
    for (int mt = 0; mt < 2; mt++)
        #pragma unroll
        for (int nt = 0; nt < 4; nt++) acc[mt][nt] = z4;

    for (int c0 = 0; c0 < C; c0 += 32) {
        #pragma unroll
        for (int p = 0; p < 4; p++) {
            int lin = p * 256 + tid, r = lin >> 2, cc = (lin & 3) * 8;
            load_lds16(zbase + (size_t)r * C + c0 + cc, Zs + lin * 8);
        }
        __syncthreads();
        bf16x8 af[2], bfv[4];
        #pragma unroll
        for (int mt = 0; mt < 2; mt++)
            af[mt] = *(const bf16x8*)&cws[(mt * 16 + l15) * 520 + c0 + q * 8];
        #pragma unroll
        for (int nt = 0; nt < 4; nt++)
            bfv[nt] = *(const bf16x8*)&Zs[(w * 64 + nt * 16 + l15) * 32 + q * 8];
        #pragma unroll
        for (int mt = 0; mt < 2; mt++)
            #pragma unroll
            for (int nt = 0; nt < 4; nt++)
                acc[mt][nt] = __builtin_amdgcn_mfma_f32_16x16x32_bf16(
                    af[mt], bfv[nt], acc[mt][nt], 0, 0, 0);
        __syncthreads();
    }

    // softmax over k (rows) for each column n
    float skv[8], c2v[8];
    #pragma unroll
    for (int mt = 0; mt < 2; mt++)
        #pragma unroll
        for (int reg = 0; reg < 4; reg++) {
            int k = mt * 16 + q * 4 + reg;
            skv[mt * 4 + reg] = scale[k];
            c2v[mt * 4 + reg] = c2[k];
        }
    float aps[8] = {};
    #pragma unroll
    for (int nt = 0; nt < 4; nt++) {
        int nglob = nb + w * 64 + nt * 16 + l15;
        float x2v = x2[(size_t)b * HW + nglob];
        float lg[8];
        float mx = -1e30f;
        #pragma unroll
        for (int mt = 0; mt < 2; mt++)
            #pragma unroll
            for (int reg = 0; reg < 4; reg++) {
                int i = mt * 4 + reg;
                float t = skv[i] * (x2v - 2.f * acc[mt][nt][reg] + c2v[i]);
                lg[i] = t;
                mx = fmaxf(mx, t);
            }
        mx = fmaxf(mx, __shfl_xor(mx, 16));
        mx = fmaxf(mx, __shfl_xor(mx, 32));
        float se = 0.f;
        #pragma unroll
        for (int i = 0; i < 8; i++) { lg[i] = __expf(lg[i] - mx); se += lg[i]; }
        se += __shfl_xor(se, 16);
        se += __shfl_xor(se, 32);
        float inv = 1.f / se;
        #pragma unroll
        for (int mt = 0; mt < 2; mt++)
            #pragma unroll
            for (int reg = 0; reg < 4; reg++) {
                int i = mt * 4 + reg;
                float a = lg[i] * inv;
                int k = mt * 16 + q * 4 + reg;
                at[((size_t)(b * K + k)) * HW + nglob] = (__bf16)a;
                aps[i] += a;
            }
    }
    #pragma unroll
    for (int mt = 0; mt < 2; mt++)
        #pragma unroll
        for (int reg = 0; reg < 4; reg++) {
            int i = mt * 4 + reg;
            float v = aps[i];
            v += __shfl_xor(v, 1);
            v += __shfl_xor(v, 2);
            v += __shfl_xor(v, 4);
            v += __shfl_xor(v, 8);
            if (l15 == 0) atomicAdd(&asum_l[mt * 16 + q * 4 + reg], v);
        }
    __syncthreads();
    if (tid < 32) atomicAdd(&asum[b * K + tid], asum_l[tid]);
}

// ---------------------------------------------------------------------------
// agg partials: part[b][chunk][k][c] = sum_{n in chunk} at[k][n] * z[n][c]
// 256 threads, each owns 2 c-columns; assign tile pre-converted to f32 in LDS.
__global__ __launch_bounds__(256) void agg_partial_kernel(
    const __bf16* __restrict__ zb, const __bf16* __restrict__ at,
    float* __restrict__ part) {
    __shared__ float ashf[32 * 256];   // 32 KB
    const int tid = threadIdx.x;
    const int b = blockIdx.y, n0 = blockIdx.x * 256;
    #pragma unroll
    for (int p = 0; p < 4; p++) {
        int lin = p * 256 + tid;
        int k = lin >> 5, nn = (lin & 31) * 8;
        bf16x8 v = *(const bf16x8*)&at[((size_t)(b * K + k)) * HW + n0 + nn];
        #pragma unroll
        for (int j = 0; j < 8; j++) ashf[k * 256 + nn + j] = (float)v[j];
    }
    __syncthreads();
    float acc0[32] = {}, acc1[32] = {};
    const __bf16* zc0 = zb + (size_t)(b * HW + n0) * C + tid;
    const __bf16* zc1 = zc0 + 256;
    for (int n = 0; n < 256; n += 2) {
        float za0 = (float)zc0[(size_t)n * C];
        float zb0 = (float)zc0[(size_t)(n + 1) * C];
        float za1 = (float)zc1[(size_t)n * C];
        float zb1 = (float)zc1[(size_t)(n + 1) * C];
        #pragma unroll
        for (int k = 0; k < 32; k++) {
            float2 ap = *(const float2*)&ashf[k * 256 + n];
            acc0[k] += ap.x * za0 + ap.y * zb0;
            acc1[k] += ap.x * za1 + ap.y * zb1;
        }
    }
    float* pp = part + ((size_t)(b * 64 + blockIdx.x) * K) * C + tid;
    #pragma unroll
    for (int k = 0; k < 32; k++) {
        pp[(size_t)k * C]       = acc0[k];
        pp[(size_t)k * C + 256] = acc1[k];
    }
}

__global__ __launch_bounds__(512) void agg_reduce_kernel(
    const float* __restrict__ part, float* __restrict__ agg) {
    const int k = blockIdx.x, b = blockIdx.y, c = threadIdx.x;
    float s = 0.f;
    for (int p = 0; p < 64; p++)
        s += part[((size_t)(b * 64 + p) * K + k) * C + c];
    agg[((size_t)(b * K) + k) * C + c] = s;
}

// ---------------------------------------------------------------------------
// feat = mean_k relu(bn1(agg - asum*cw)); gamma = sigmoid(fc_w @ feat + fc_b)
__global__ __launch_bounds__(512) void feat_kernel(
    const float* __restrict__ cw,
    const float* __restrict__ g1, const float* __restrict__ b1,
    const float* __restrict__ m1, const float* __restrict__ v1,
    const float* __restrict__ fcw, const float* __restrict__ fcb,
    const float* __restrict__ agg, const float* __restrict__ asum,
    float* __restrict__ gamma, float* __restrict__ out_feat) {
    __shared__ float featL[C];
    const int tid = threadIdx.x;
    const int b = blockIdx.x;
    float f = 0.f;
    for (int kk = 0; kk < K; kk++) {
        float s = g1[kk] * rsqrtf(v1[kk] + EPS);
        float bias = b1[kk] - m1[kk] * s;
        float e = agg[((size_t)b * K + kk) * C + tid] - asum[b * K + kk] * cw[kk * C + tid];
        f += fmaxf(e * s + bias, 0.f);
    }
    f *= (1.f / 32.f);
    out_feat[b * C + tid] = f;
    featL[tid] = f;
    __syncthreads();
    const int w = tid >> 6, l = tid & 63;
    for (int cc = w * 64; cc < w * 64 + 64; cc++) {
        const float* row = &fcw[(size_t)cc * C + l * 8];
        float4 fa = *(const float4*)&featL[l * 8];
        float4 fb = *(const float4*)&featL[l * 8 + 4];
        float4 wa = *(const float4*)row;
        float4 wb = *(const float4*)(row + 4);
        float s = fa.x * wa.x + fa.y * wa.y + fa.z * wa.z + fa.w * wa.w
                + fb.x * wb.x + fb.y * wb.y + fb.z * wb.z + fb.w * wb.w;
        #pragma unroll
        for (int d = 32; d >= 1; d >>= 1) s += __shfl_xor(s, d);
        if (l == 0) gamma[b * C + cc] = 1.f / (1.f + __expf(-(s + fcb[cc])));
    }
}

// ---------------------------------------------------------------------------
// out = relu(x * (1 + gamma[b,c]))
__global__ __launch_bounds__(256) void gate_kernel(const float* __restrict__ x,
                                                   const float* __restrict__ gamma,
                                                   float* __restrict__ out) {
    size_t idx = (size_t)blockIdx.x * 256 + threadIdx.x;
    int bc = (int)(idx >> 12);
    float gm = 1.f + gamma[bc];
    float4 xv = ((const float4*)x)[idx];
    float4 r;
    r.x = fmaxf(xv.x * gm, 0.f);
    r.y = fmaxf(xv.y * gm, 0.f);
    r.z = fmaxf(xv.z * gm, 0.f);
    r.w = fmaxf(xv.w * gm, 0.f);
    ((float4*)out)[idx] = r;
}

// ---------------------------------------------------------------------------
extern "C" void kernel_launch(void* const* d_in, const int* in_sizes, int n_in,
                              void* d_out, int out_size, void* d_ws, size_t ws_size,
                              hipStream_t stream) {
    const float* x      = (const float*)d_in[0];
    const float* conv_w = (const float*)d_in[1];
    const float* bn2_g  = (const float*)d_in[2];
    const float* bn2_b  = (const float*)d_in[3];
    const float* bn2_m  = (const float*)d_in[4];
    const float* bn2_v  = (const float*)d_in[5];
    const float* cw     = (const float*)d_in[6];
    const float* scale  = (const float*)d_in[7];
    const float* bn1_g  = (const float*)d_in[8];
    const float* bn1_b  = (const float*)d_in[9];
    const float* bn1_m  = (const float*)d_in[10];
    const float* bn1_v  = (const float*)d_in[11];
    const float* fcw    = (const float*)d_in[12];
    const float* fcb    = (const float*)d_in[13];
    char* wsb = (char*)d_ws;
    __bf16* xb   = (__bf16*)(wsb + XB_OFF);
    float*  part = (float*)(wsb + PART_OFF);
    float*  agg  = (float*)(wsb + AGG_OFF);
    float*  gamma= (float*)(wsb + GAMMA_OFF);
    __bf16* zbuf = (__bf16*)(wsb + ZB_OFF);
    __bf16* wbb  = (__bf16*)(wsb + WBB_OFF);
    __bf16* cwb  = (__bf16*)(wsb + CWB_OFF);
    __bf16* at   = (__bf16*)(wsb + AT_OFF);
    float*  x2   = (float*)(wsb + X2_OFF);
    float*  c2   = (float*)(wsb + C2_OFF);
    float*  asum = (float*)(wsb + ASUM_OFF);
    float* out = (float*)d_out;

    prep_kernel<<<69, 256, 0, stream>>>(conv_w, cw, wbb, cwb, c2, asum);
    transpose_cvt_kernel<<<dim3(256, 8, 4), 256, 0, stream>>>(x, xb);
    conv_gemm_kernel<<<dim3(128, 4, 4), 256, 0, stream>>>(
        xb, wbb, bn2_g, bn2_b, bn2_m, bn2_v, zbuf);
    x2_kernel<<<16384, 256, 0, stream>>>(zbuf, x2);
    assign_mfma_kernel<<<dim3(64, 4), 256, 0, stream>>>(
        zbuf, cwb, scale, c2, x2, at, asum);
    agg_partial_kernel<<<dim3(64, 4), 256, 0, stream>>>(zbuf, at, part);
    agg_reduce_kernel<<<dim3(32, 4), 512, 0, stream>>>(part, agg);
    feat_kernel<<<4, 512, 0, stream>>>(cw, bn1_g, bn1_b, bn1_m, bn1_v,
                                       fcw, fcb, agg, asum, gamma, out);
    gate_kernel<<<32768, 256, 0, stream>>>(x, gamma, out + B * C);
}

// Round 3
// 477.937 us; speedup vs baseline: 1.7765x; 1.0819x over previous
//
#include <hip/hip_runtime.h>
#include <cstdint>

#define EPS 1e-5f
constexpr int B = 4, C = 512, HW = 16384, K = 32;

typedef __bf16 bf16x8 __attribute__((ext_vector_type(8)));
typedef float  floatx4 __attribute__((ext_vector_type(4)));
typedef unsigned int u32;

__device__ __forceinline__ void load_lds16(const void* g, void* l) {
    __builtin_amdgcn_global_load_lds((const __attribute__((address_space(1))) u32*)g,
                                     (__attribute__((address_space(3))) u32*)l,
                                     16, 0, 0);
}

// ---------------------------------------------------------------------------
// workspace byte offsets
constexpr size_t Z_OFF     = 0;            // z bf16 [b][n][c]    67,108,864
constexpr size_t WBB_OFF   = 67108864;     // W bf16 [o][c]          524,288
constexpr size_t CWB_OFF   = 67633152;     // cw bf16 [k][c]          32,768
constexpr size_t X2_OFF    = 67665920;     // fp32 [b*HW]            262,144
constexpr size_t C2_OFF    = 67928064;     // fp32 [K]
constexpr size_t ASUM_OFF  = 67928192;     // fp32 [B*K]
constexpr size_t PART_OFF  = 67928704;     // fp32 [B][128][K][C] 33,554,432
constexpr size_t AGG_OFF   = 101483136;    // fp32 [B][K][C]         262,144
constexpr size_t GAMMA_OFF = 101745280;    // fp32 [B][C]

// ---------------------------------------------------------------------------
// prep: convert conv_w and codewords to bf16; c2[k]; zero asum
__global__ __launch_bounds__(256) void prep_kernel(
    const float* __restrict__ conv_w, const float* __restrict__ cw,
    __bf16* __restrict__ wbb, __bf16* __restrict__ cwb,
    float* __restrict__ c2, float* __restrict__ asum) {
    const int tid = threadIdx.x;
    if (blockIdx.x < 68) {
        int idx = (blockIdx.x * 256 + tid) * 16;
        const float* s;
        __bf16* d;
        if (idx < 262144) { s = conv_w + idx; d = wbb + idx; }
        else              { s = cw + (idx - 262144); d = cwb + (idx - 262144); }
        bf16x8 o0, o1;
        #pragma unroll
        for (int j = 0; j < 8; j++) o0[j] = (__bf16)s[j];
        #pragma unroll
        for (int j = 0; j < 8; j++) o1[j] = (__bf16)s[8 + j];
        *(bf16x8*)&d[0] = o0;
        *(bf16x8*)&d[8] = o1;
    } else {
        if (tid < 32) {
            const float* r = cw + tid * 512;
            float s = 0.f;
            for (int c = 0; c < 512; c++) s += r[c] * r[c];
            c2[tid] = s;
        }
        if (tid < 128) asum[tid] = 0.f;
    }
}

// ---------------------------------------------------------------------------
// fused: transpose x (in LDS) + conv GEMM (bf16 MFMA) + BN2 + ReLU + x2.
// block: 64 n x full 512 o; 4 waves each 64n x 128o (acc 128 regs/lane).
// x chunk fp32 staged [c][n] via global_load_lds; transposed to XA [n][c] bf16
// (row stride 72 el -> 16B aligned b128 frags); W read per-fragment from L2.
__global__ __launch_bounds__(256) void conv_fused_kernel(
    const float* __restrict__ x, const __bf16* __restrict__ wbb,
    const float* __restrict__ g2, const float* __restrict__ b2,
    const float* __restrict__ m2, const float* __restrict__ v2,
    __bf16* __restrict__ z, float* __restrict__ x2g) {
    __shared__ float  XR[2][64 * 64];   // [chunk c][n] fp32, 2x16 KB
    __shared__ __bf16 XA[2][64 * 72];   // [n][c-in-chunk], 2x9 KB
    __shared__ float  x2L[64];
    const int tid = threadIdx.x, lane = tid & 63, w = tid >> 6;
    const int l15 = lane & 15, q = lane >> 4;
    const int n0 = blockIdx.x * 64, b = blockIdx.y;
    if (tid < 64) x2L[tid] = 0.f;

    auto stage = [&](int chunk, int buf) {
        #pragma unroll
        for (int p = 0; p < 4; p++) {
            int seg = w * 4 + p;                    // 16 segs of 4 c-rows
            int cr = chunk * 64 + seg * 4 + (lane >> 4);
            const float* gp = x + ((size_t)(b * C + cr)) * HW + n0 + (lane & 15) * 4;
            load_lds16(gp, (char*)XR[buf] + seg * 1024);
        }
    };

    floatx4 acc[4][8];
    const floatx4 zv4 = {0.f, 0.f, 0.f, 0.f};
    #pragma unroll
    for (int mt = 0; mt < 4; mt++)
        #pragma unroll
        for (int ot = 0; ot < 8; ot++) acc[mt][ot] = zv4;

    stage(0, 0);
    for (int i = 0; i < 8; i++) {
        const int buf = i & 1;
        __syncthreads();                    // XR[buf] loads drained
        if (i < 7) stage(i + 1, buf ^ 1);   // prefetch next chunk
        // transpose+convert XR[buf] -> XA[buf]
        #pragma unroll
        for (int f = 0; f < 2; f++) {
            int id = f * 256 + tid;
            int n = id & 63, cs = id >> 6;
            bf16x8 o;
            #pragma unroll
            for (int j = 0; j < 8; j++) o[j] = (__bf16)XR[buf][(cs * 8 + j) * 64 + n];
            *(bf16x8*)&XA[buf][n * 72 + cs * 8] = o;
        }
        __syncthreads();                    // XA[buf] ready
        #pragma unroll
        for (int ks = 0; ks < 2; ks++) {
            bf16x8 af[4], bfv[8];
            #pragma unroll
            for (int mt = 0; mt < 4; mt++)
                af[mt] = *(const bf16x8*)&XA[buf][(mt * 16 + l15) * 72 + ks * 32 + q * 8];
            #pragma unroll
            for (int ot = 0; ot < 8; ot++)
                bfv[ot] = *(const bf16x8*)&wbb[(size_t)(w * 128 + ot * 16 + l15) * C
                                               + i * 64 + ks * 32 + q * 8];
            #pragma unroll
            for (int mt = 0; mt < 4; mt++)
                #pragma unroll
                for (int ot = 0; ot < 8; ot++)
                    acc[mt][ot] = __builtin_amdgcn_mfma_f32_16x16x32_bf16(
                        af[mt], bfv[ot], acc[mt][ot], 0, 0, 0);
        }
    }
    // epilogue: BN + ReLU + store z bf16 + x2 partials
    float s8[8], bi8[8];
    #pragma unroll
    for (int ot = 0; ot < 8; ot++) {
        int o = w * 128 + ot * 16 + l15;
        float s = g2[o] * rsqrtf(v2[o] + EPS);
        s8[ot] = s; bi8[ot] = b2[o] - m2[o] * s;
    }
    float xx[16];
    #pragma unroll
    for (int t = 0; t < 16; t++) xx[t] = 0.f;
    #pragma unroll
    for (int mt = 0; mt < 4; mt++)
        #pragma unroll
        for (int reg = 0; reg < 4; reg++) {
            int n = n0 + mt * 16 + q * 4 + reg;
            #pragma unroll
            for (int ot = 0; ot < 8; ot++) {
                float v = fmaxf(acc[mt][ot][reg] * s8[ot] + bi8[ot], 0.f);
                z[((size_t)(b * HW + n)) * C + w * 128 + ot * 16 + l15] = (__bf16)v;
                xx[mt * 4 + reg] += v * v;
            }
        }
    #pragma unroll
    for (int t = 0; t < 16; t++) {
        float v = xx[t];
        v += __shfl_xor(v, 1); v += __shfl_xor(v, 2);
        v += __shfl_xor(v, 4); v += __shfl_xor(v, 8);
        xx[t] = v;
    }
    if (l15 == 0) {
        #pragma unroll
        for (int mt = 0; mt < 4; mt++)
            #pragma unroll
            for (int reg = 0; reg < 4; reg++)
                atomicAdd(&x2L[mt * 16 + q * 4 + reg], xx[mt * 4 + reg]);
    }
    __syncthreads();
    if (tid < 64) x2g[(size_t)b * HW + n0 + tid] = x2L[tid];
}

// ---------------------------------------------------------------------------
// fused assign+agg: per block 128 n (4 sub-tiles of 32).
// per sub-tile: stage z[32][512] in LDS (pad to 528) -> assign MFMA (cw from
// global/L1) -> in-LDS logit exchange -> softmax -> AT [k][n] bf16 in LDS ->
// agg MFMA (A=AT contiguous, B=z^T strided u16). agg acc persists in VGPRs.
__global__ __launch_bounds__(256) void assign_agg_kernel(
    const __bf16* __restrict__ zb, const __bf16* __restrict__ cwb,
    const float* __restrict__ scale, const float* __restrict__ c2,
    const float* __restrict__ x2g, float* __restrict__ part,
    float* __restrict__ asum) {
    __shared__ __bf16 ZT[32][528];   // 33 KB
    __shared__ float  LG[32][33];    // logits [k][n]
    __shared__ __bf16 AT[32][40];    // assign [k][n]
    __shared__ float  asum_l[32];
    const int tid = threadIdx.x, lane = tid & 63, w = tid >> 6;
    const int l15 = lane & 15, q = lane >> 4;
    const int b = blockIdx.y, bx = blockIdx.x;
    if (tid < 32) asum_l[tid] = 0.f;
    float sck[8], c2k[8];
    #pragma unroll
    for (int j = 0; j < 8; j++) { sck[j] = scale[q * 8 + j]; c2k[j] = c2[q * 8 + j]; }
    const int mt_ = w >> 1, nt_ = w & 1;

    floatx4 agga[2][8];
    const floatx4 zv4 = {0.f, 0.f, 0.f, 0.f};
    #pragma unroll
    for (int mt = 0; mt < 2; mt++)
        #pragma unroll
        for (int ct = 0; ct < 8; ct++) agga[mt][ct] = zv4;

    for (int s = 0; s < 4; s++) {
        const int nb = bx * 128 + s * 32;
        bf16x8 st[8];
        #pragma unroll
        for (int p = 0; p < 8; p++) {
            int e = (p * 256 + tid) * 8;
            int n = e >> 9, c = e & 511;
            st[p] = *(const bf16x8*)&zb[((size_t)(b * HW + nb + n)) * C + c];
        }
        __syncthreads();   // prev sub-tile compute done reading ZT
        #pragma unroll
        for (int p = 0; p < 8; p++) {
            int e = (p * 256 + tid) * 8;
            int n = e >> 9, c = e & 511;
            *(bf16x8*)&ZT[n][c] = st[p];
        }
        __syncthreads();
        // ---- assign MFMA: each wave one (mt_, nt_) 16x16 tile, full K=512
        floatx4 la = zv4;
        #pragma unroll
        for (int kc = 0; kc < 16; kc++) {
            bf16x8 a  = *(const bf16x8*)&cwb[(size_t)(mt_ * 16 + l15) * C + kc * 32 + q * 8];
            bf16x8 bb = *(const bf16x8*)&ZT[nt_ * 16 + l15][kc * 32 + q * 8];
            la = __builtin_amdgcn_mfma_f32_16x16x32_bf16(a, bb, la, 0, 0, 0);
        }
        #pragma unroll
        for (int r = 0; r < 4; r++)
            LG[mt_ * 16 + q * 4 + r][nt_ * 16 + l15] = la[r];
        __syncthreads();
        // ---- softmax over k (waves 0,1 cover the 32 n-columns)
        if (w < 2) {
            int nl = w * 16 + l15;
            float x2v = x2g[(size_t)b * HW + nb + nl];
            float lg[8];
            float mx = -1e30f;
            #pragma unroll
            for (int j = 0; j < 8; j++) {
                float t = sck[j] * (x2v - 2.f * LG[q * 8 + j][nl] + c2k[j]);
                lg[j] = t; mx = fmaxf(mx, t);
            }
            mx = fmaxf(mx, __shfl_xor(mx, 16));
            mx = fmaxf(mx, __shfl_xor(mx, 32));
            float se = 0.f;
            #pragma unroll
            for (int j = 0; j < 8; j++) { lg[j] = __expf(lg[j] - mx); se += lg[j]; }
            se += __shfl_xor(se, 16);
            se += __shfl_xor(se, 32);
            float inv = 1.f / se;
            #pragma unroll
            for (int j = 0; j < 8; j++) {
                float a = lg[j] * inv;
                AT[q * 8 + j][nl] = (__bf16)a;
                lg[j] = a;
            }
            #pragma unroll
            for (int j = 0; j < 8; j++) {
                float v = lg[j];
                v += __shfl_xor(v, 1); v += __shfl_xor(v, 2);
                v += __shfl_xor(v, 4); v += __shfl_xor(v, 8);
                if (l15 == 0) atomicAdd(&asum_l[q * 8 + j], v);
            }
        }
        __syncthreads();
        // ---- agg MFMA: Kdim = 32 n (one chunk); per wave 8 c-tiles
        bf16x8 afr0 = *(const bf16x8*)&AT[l15][q * 8];
        bf16x8 afr1 = *(const bf16x8*)&AT[16 + l15][q * 8];
        #pragma unroll
        for (int ct = 0; ct < 8; ct++) {
            int c = w * 128 + ct * 16 + l15;
            bf16x8 bb;
            #pragma unroll
            for (int j = 0; j < 8; j++) bb[j] = ZT[q * 8 + j][c];
            agga[0][ct] = __builtin_amdgcn_mfma_f32_16x16x32_bf16(afr0, bb, agga[0][ct], 0, 0, 0);
            agga[1][ct] = __builtin_amdgcn_mfma_f32_16x16x32_bf16(afr1, bb, agga[1][ct], 0, 0, 0);
        }
    }
    // epilogue: per-block agg partials
    float* pp = part + ((size_t)(b * 128 + bx) * K) * C;
    #pragma unroll
    for (int mt = 0; mt < 2; mt++)
        #pragma unroll
        for (int ct = 0; ct < 8; ct++)
            #pragma unroll
            for (int r = 0; r < 4; r++)
                pp[(size_t)(mt * 16 + q * 4 + r) * C + w * 128 + ct * 16 + l15] =
                    agga[mt][ct][r];
    __syncthreads();
    if (tid < 32) atomicAdd(&asum[b * K + tid], asum_l[tid]);
}

// ---------------------------------------------------------------------------
__global__ __launch_bounds__(512) void agg_reduce_kernel(
    const float* __restrict__ part, float* __restrict__ agg) {
    const int k = blockIdx.x, b = blockIdx.y, c = threadIdx.x;
    float s = 0.f;
    for (int p = 0; p < 128; p++)
        s += part[((size_t)((b * 128 + p) * K + k)) * C + c];
    agg[((size_t)(b * K + k)) * C + c] = s;
}

// ---------------------------------------------------------------------------
// feat = mean_k relu(bn1(agg - asum*cw)); gamma = sigmoid(fc_w @ feat + fc_b)
__global__ __launch_bounds__(512) void feat_kernel(
    const float* __restrict__ cw,
    const float* __restrict__ g1, const float* __restrict__ b1,
    const float* __restrict__ m1, const float* __restrict__ v1,
    const float* __restrict__ fcw, const float* __restrict__ fcb,
    const float* __restrict__ agg, const float* __restrict__ asum,
    float* __restrict__ gamma, float* __restrict__ out_feat) {
    __shared__ float featL[C];
    const int tid = threadIdx.x;
    const int b = blockIdx.x;
    float f = 0.f;
    for (int kk = 0; kk < K; kk++) {
        float s = g1[kk] * rsqrtf(v1[kk] + EPS);
        float bias = b1[kk] - m1[kk] * s;
        float e = agg[((size_t)b * K + kk) * C + tid] - asum[b * K + kk] * cw[kk * C + tid];
        f += fmaxf(e * s + bias, 0.f);
    }
    f *= (1.f / 32.f);
    out_feat[b * C + tid] = f;
    featL[tid] = f;
    __syncthreads();
    const int w = tid >> 6, l = tid & 63;
    for (int cc = w * 64; cc < w * 64 + 64; cc++) {
        const float* row = &fcw[(size_t)cc * C + l * 8];
        float4 fa = *(const float4*)&featL[l * 8];
        float4 fb = *(const float4*)&featL[l * 8 + 4];
        float4 wa = *(const float4*)row;
        float4 wb = *(const float4*)(row + 4);
        float s = fa.x * wa.x + fa.y * wa.y + fa.z * wa.z + fa.w * wa.w
                + fb.x * wb.x + fb.y * wb.y + fb.z * wb.z + fb.w * wb.w;
        #pragma unroll
        for (int d = 32; d >= 1; d >>= 1) s += __shfl_xor(s, d);
        if (l == 0) gamma[b * C + cc] = 1.f / (1.f + __expf(-(s + fcb[cc])));
    }
}

// ---------------------------------------------------------------------------
// out = relu(x * (1 + gamma[b,c]))
__global__ __launch_bounds__(256) void gate_kernel(const float* __restrict__ x,
                                                   const float* __restrict__ gamma,
                                                   float* __restrict__ out) {
    size_t idx = (size_t)blockIdx.x * 256 + threadIdx.x;
    int bc = (int)(idx >> 12);
    float gm = 1.f + gamma[bc];
    float4 xv = ((const float4*)x)[idx];
    float4 r;
    r.x = fmaxf(xv.x * gm, 0.f);
    r.y = fmaxf(xv.y * gm, 0.f);
    r.z = fmaxf(xv.z * gm, 0.f);
    r.w = fmaxf(xv.w * gm, 0.f);
    ((float4*)out)[idx] = r;
}

// ---------------------------------------------------------------------------
extern "C" void kernel_launch(void* const* d_in, const int* in_sizes, int n_in,
                              void* d_out, int out_size, void* d_ws, size_t ws_size,
                              hipStream_t stream) {
    const float* x      = (const float*)d_in[0];
    const float* conv_w = (const float*)d_in[1];
    const float* bn2_g  = (const float*)d_in[2];
    const float* bn2_b  = (const float*)d_in[3];
    const float* bn2_m  = (const float*)d_in[4];
    const float* bn2_v  = (const float*)d_in[5];
    const float* cw     = (const float*)d_in[6];
    const float* scale  = (const float*)d_in[7];
    const float* bn1_g  = (const float*)d_in[8];
    const float* bn1_b  = (const float*)d_in[9];
    const float* bn1_m  = (const float*)d_in[10];
    const float* bn1_v  = (const float*)d_in[11];
    const float* fcw    = (const float*)d_in[12];
    const float* fcb    = (const float*)d_in[13];
    char* wsb = (char*)d_ws;
    __bf16* zbuf  = (__bf16*)(wsb + Z_OFF);
    __bf16* wbb   = (__bf16*)(wsb + WBB_OFF);
    __bf16* cwb   = (__bf16*)(wsb + CWB_OFF);
    float*  x2    = (float*)(wsb + X2_OFF);
    float*  c2    = (float*)(wsb + C2_OFF);
    float*  asum  = (float*)(wsb + ASUM_OFF);
    float*  part  = (float*)(wsb + PART_OFF);
    float*  agg   = (float*)(wsb + AGG_OFF);
    float*  gamma = (float*)(wsb + GAMMA_OFF);
    float* out = (float*)d_out;

    prep_kernel<<<69, 256, 0, stream>>>(conv_w, cw, wbb, cwb, c2, asum);
    conv_fused_kernel<<<dim3(256, 4), 256, 0, stream>>>(
        x, wbb, bn2_g, bn2_b, bn2_m, bn2_v, zbuf, x2);
    assign_agg_kernel<<<dim3(128, 4), 256, 0, stream>>>(
        zbuf, cwb, scale, c2, x2, part, asum);
    agg_reduce_kernel<<<dim3(32, 4), 512, 0, stream>>>(part, agg);
    feat_kernel<<<4, 512, 0, stream>>>(cw, bn1_g, bn1_b, bn1_m, bn1_v,
                                       fcw, fcb, agg, asum, gamma, out);
    gate_kernel<<<32768, 256, 0, stream>>>(x, gamma, out + B * C);
}